// Round 4
// baseline (503.155 us; speedup 1.0000x reference)
//
#include <hip/hip_runtime.h>
#include <hip/hip_bf16.h>

// Shapes
#define B_    64
#define C_    768
#define T_    1024
#define K_    800
#define KPAD  896     // pad 800 -> 7 * 128
#define MT    64      // token rows per block
#define NT    128     // proto cols per n-tile
#define NTILES 7      // KPAD / NT
#define KSTEPS 12     // C_ / 64
#define NSTEPS 84     // NTILES * KSTEPS
#define TCH   16      // T_ / MT

using bf16x8 = __attribute__((ext_vector_type(8))) short;
using f32x4  = __attribute__((ext_vector_type(4))) float;

__device__ __forceinline__ void gload16(const void* g, void* lds) {
    __builtin_amdgcn_global_load_lds(
        (const __attribute__((address_space(1))) unsigned int*)g,
        (__attribute__((address_space(3))) unsigned int*)lds, 16, 0, 0);
}
__device__ __forceinline__ unsigned swz8(unsigned t) { return (t & 7) ^ ((t >> 3) & 7); }

// ---------------- kernel P: normalize prototypes -> bf16, pad rows 800..895 with 0
__global__ __launch_bounds__(64) void proto_norm_kernel(const float* __restrict__ protos,
                                                        unsigned short* __restrict__ pn) {
    const int row = blockIdx.x;
    const int l = threadIdx.x;
    if (row >= K_) {
        for (int i = 0; i < 12; ++i) pn[(size_t)row * C_ + l + 64 * i] = 0;
        return;
    }
    float v[12];
    float ss = 0.f;
    for (int i = 0; i < 12; ++i) {
        v[i] = protos[(size_t)row * C_ + l + 64 * i];
        ss += v[i] * v[i];
    }
    for (int off = 32; off >= 1; off >>= 1) ss += __shfl_xor(ss, off);
    const float scale = 1.0f / fmaxf(sqrtf(ss), 1e-6f);
    for (int i = 0; i < 12; ++i) {
        __hip_bfloat16 h = __float2bfloat16(v[i] * scale);
        pn[(size_t)row * C_ + l + 64 * i] = *reinterpret_cast<unsigned short*>(&h);
    }
}

// ---------------- kernel A: build bf16 A-image (pre-swizzled, slice-major) + token scales
// Image per 64-token chunk: [ks 0..11][t 0..63][slot j 0..7][16B], slot j holds
// c-chunk (j ^ swz8(t)) of slice ks (8 bf16 in c-order).
__global__ __launch_bounds__(512) void feats_img_kernel(
        const float* __restrict__ feats, const float* __restrict__ log_temp,
        unsigned short* __restrict__ img, float* __restrict__ scale) {
    __shared__ char  A[98304];
    __shared__ float ss[64];
    const int tid = threadIdx.x;
    const int bb = blockIdx.x >> 4, tc = blockIdx.x & 15;
    const int t0 = tc * 64;
    if (tid < 64) ss[tid] = 0.f;
    __syncthreads();

    const int t4 = tid & 15;      // float4 index along t
    const int cq = tid >> 4;      // 0..31
    float ssp[4] = {0.f, 0.f, 0.f, 0.f};
    const float* fb = feats + (size_t)bb * (C_ * T_) + t0 + t4 * 4;
    #pragma unroll
    for (int i = 0; i < 6; ++i) {
        const int c0 = cq * 4 + i * 128;
        unsigned short hb[4][4];
        #pragma unroll
        for (int j = 0; j < 4; ++j) {
            const float4 v = *reinterpret_cast<const float4*>(fb + (size_t)(c0 + j) * T_);
            const float e[4] = {v.x, v.y, v.z, v.w};
            #pragma unroll
            for (int q = 0; q < 4; ++q) {
                ssp[q] += e[q] * e[q];
                __hip_bfloat16 h = __float2bfloat16(e[q]);
                hb[q][j] = *reinterpret_cast<unsigned short*>(&h);
            }
        }
        const int ks = c0 >> 6, cc = (c0 >> 3) & 7, half = (c0 >> 2) & 1;
        #pragma unroll
        for (int q = 0; q < 4; ++q) {
            const int t = t4 * 4 + q;
            const unsigned byte = (unsigned)(ks * 8192 + t * 128 + ((cc ^ swz8(t)) << 4) + half * 8);
            ushort4 pk = {hb[q][0], hb[q][1], hb[q][2], hb[q][3]};
            *reinterpret_cast<ushort4*>(&A[byte]) = pk;
        }
    }
    #pragma unroll
    for (int q = 0; q < 4; ++q) {
        ssp[q] += __shfl_xor(ssp[q], 16);
        ssp[q] += __shfl_xor(ssp[q], 32);
    }
    if ((tid & 63) < 16) {
        #pragma unroll
        for (int q = 0; q < 4; ++q) atomicAdd(&ss[(tid & 63) * 4 + q], ssp[q]);
    }
    __syncthreads();
    if (tid < 64) {
        const float temp = fminf(fmaxf(expf(log_temp[0]), 1e-4f), 100.0f);
        scale[blockIdx.x * 64 + tid] = temp / fmaxf(sqrtf(ss[tid]), 1e-6f);
    }
    // linear coalesced dump of the image
    unsigned short* ob = img + (size_t)blockIdx.x * 49152;
    #pragma unroll
    for (int k = 0; k < 12; ++k) {
        bf16x8 v = *reinterpret_cast<const bf16x8*>(&A[k * 8192 + tid * 16]);
        *reinterpret_cast<bf16x8*>(ob + k * 4096 + tid * 8) = v;
    }
}

// ---------------- main kernel: fully-async A (progressive slices) + B (triple buffer),
// counted vmcnt pipeline, online partial LSE per nt-tile.
__global__ __launch_bounds__(512, 1) void main_kernel(
        const unsigned short* __restrict__ img, const unsigned short* __restrict__ pn,
        const float* __restrict__ scale,
        float* __restrict__ wsm, float* __restrict__ wss) {

    __shared__ char  Aim[98304];            // 12 slices x [t][slot] (image layout)
    __shared__ char  Blds[3 * 16384];       // 3 bufs of [n][8 slots*16B]
    __shared__ float red[8][2][16][2];
    __shared__ float res[KPAD * 2];         // deferred (M,S)

    const int tid = threadIdx.x;
    const int l   = tid & 63;
    const int w   = tid >> 6;
    const int g   = l >> 4;
    const int lm  = l & 15;
    const int wm  = w >> 2;
    const int wn  = w & 3;
    const int chunk = blockIdx.x;           // = bb*16 + tc

    // B staging: linear LDS dest, pre-swizzled global source (slot j <- chunk j^(n&7))
    const int sSlot8  = (((l & 7) ^ ((l >> 3) & 7))) * 8;
    const int rowLane = (w * 16 + (l >> 3)) * C_ + sSlot8;
    auto stageB = [&](int rowBase, int colOff, int bufi) {
        const unsigned short* gp = pn + rowBase + rowLane + colOff;
        char* lb = &Blds[bufi * 16384 + w * 2048];
        gload16(gp, lb);
        gload16(gp + 8 * C_, lb + 1024);
    };
    // A staging: image is already the LDS layout -> straight linear copy
    const unsigned short* ib = img + (size_t)chunk * 49152;
    auto stageA = [&](int ks) {
        gload16(ib + ks * 4096 + tid * 8, &Aim[ks * 8192 + tid * 16]);
    };

    // per-thread scale fragments (uniform 2 loads/thread; safe vs vmcnt counting)
    const float4 scv0 = *reinterpret_cast<const float4*>(scale + chunk * 64 + wm * 32 + g * 4);
    const float4 scv1 = *reinterpret_cast<const float4*>(scale + chunk * 64 + wm * 32 + 16 + g * 4);

    // prologue: A(0),B(0),A(1),B(1) in flight
    stageA(0); stageB(0, 0, 0);
    stageA(1); stageB(0, 64, 1);

    int bufC = 0;           // compute buffer = u % 3
    int sRB  = 0, sKS = 2;  // next B-stage coords (u+2)

    for (int nt = 0; nt < NTILES; ++nt) {
        f32x4 acc[2][2] = {};

        for (int ks = 0; ks < KSTEPS; ++ks) {
            const int u = nt * KSTEPS + ks;
            if (u <= 10)      asm volatile("s_waitcnt vmcnt(3)" ::: "memory");
            else if (u <= 82) asm volatile("s_waitcnt vmcnt(2)" ::: "memory");
            else              asm volatile("s_waitcnt vmcnt(0)" ::: "memory");
            __builtin_amdgcn_s_barrier();

            bf16x8 a[2][2], b[2][2];
            #pragma unroll
            for (int kk = 0; kk < 2; ++kk) {
                #pragma unroll
                for (int mi = 0; mi < 2; ++mi) {
                    const int t = wm * 32 + mi * 16 + lm;
                    const unsigned byte =
                        (unsigned)(ks * 8192 + t * 128 + (((kk * 4 + g) ^ swz8(t)) << 4));
                    a[kk][mi] = *reinterpret_cast<const bf16x8*>(&Aim[byte]);
                }
                #pragma unroll
                for (int ni = 0; ni < 2; ++ni) {
                    const int n = wn * 32 + ni * 16 + lm;
                    const int j = (kk * 4 + g) ^ (n & 7);
                    b[kk][ni] = *reinterpret_cast<const bf16x8*>(
                        &Blds[bufC * 16384 + n * 128 + j * 16]);
                }
            }

            // prefetch distance 2 (A only while building the panel during nt=0)
            if (u + 2 <= 11) stageA(u + 2);
            if (u + 2 <= 83) {
                const int bufS = (bufC == 0) ? 2 : bufC - 1;
                stageB(sRB, sKS * 64, bufS);
                if (++sKS == KSTEPS) { sKS = 0; sRB += NT * C_; }
            }

            __builtin_amdgcn_s_setprio(1);
            #pragma unroll
            for (int kk = 0; kk < 2; ++kk)
                #pragma unroll
                for (int mi = 0; mi < 2; ++mi)
                    #pragma unroll
                    for (int ni = 0; ni < 2; ++ni)
                        acc[mi][ni] = __builtin_amdgcn_mfma_f32_16x16x32_bf16(
                            a[kk][mi], b[kk][ni], acc[mi][ni], 0, 0, 0);
            __builtin_amdgcn_s_setprio(0);

            bufC = (bufC == 2) ? 0 : bufC + 1;
        }

        // ---- epilogue: scale by temp/||token||, partial LSE over the 64 t-rows
        #pragma unroll
        for (int ni = 0; ni < 2; ++ni) {
            float vals[8];
            float mloc = -3.0e38f;
            #pragma unroll
            for (int mi = 0; mi < 2; ++mi) {
                const float4 sc = mi ? scv1 : scv0;
                const float scv[4] = {sc.x, sc.y, sc.z, sc.w};
                #pragma unroll
                for (int r = 0; r < 4; ++r) {
                    const float v = acc[mi][ni][r] * scv[r];
                    vals[mi * 4 + r] = v;
                    mloc = fmaxf(mloc, v);
                }
            }
            float sloc = 0.f;
            #pragma unroll
            for (int i = 0; i < 8; ++i) sloc += expf(vals[i] - mloc);
            #pragma unroll
            for (int off = 16; off <= 32; off <<= 1) {
                const float mo = __shfl_xor(mloc, off);
                const float so = __shfl_xor(sloc, off);
                const float M = fmaxf(mloc, mo);
                sloc = sloc * expf(mloc - M) + so * expf(mo - M);
                mloc = M;
            }
            if (l < 16) { red[w][ni][lm][0] = mloc; red[w][ni][lm][1] = sloc; }
        }
        asm volatile("s_waitcnt lgkmcnt(0)" ::: "memory");
        __builtin_amdgcn_s_barrier();
        if (wm == 0 && l < 16) {
            #pragma unroll
            for (int ni = 0; ni < 2; ++ni) {
                const float m0 = red[w][ni][lm][0],     s0 = red[w][ni][lm][1];
                const float m1 = red[w + 4][ni][lm][0], s1 = red[w + 4][ni][lm][1];
                const float M = fmaxf(m0, m1);
                const float S = s0 * expf(m0 - M) + s1 * expf(m1 - M);
                const int r = nt * NT + wn * 32 + ni * 16 + lm;
                res[r * 2 + 0] = M;
                res[r * 2 + 1] = S;
            }
        }
        // red/res reuse protected by the next step's top-of-loop barrier
    }

    asm volatile("s_waitcnt lgkmcnt(0)" ::: "memory");
    __builtin_amdgcn_s_barrier();

    const size_t wsbase = (size_t)chunk * KPAD;
    for (int e = tid; e < KPAD; e += 512) {
        wsm[wsbase + e] = res[e * 2 + 0];
        wss[wsbase + e] = res[e * 2 + 1];
    }
}

// ---------------- final: joint LSE over 16 chunks x 8 protos per class
__global__ __launch_bounds__(128) void final_kernel(const float* __restrict__ wsm,
                                                    const float* __restrict__ wss,
                                                    float* __restrict__ out) {
    const int b = blockIdx.x;
    const int c = threadIdx.x;
    if (c >= 100) return;
    float M = -3.0e38f, S = 0.f;
    for (int ch = 0; ch < TCH; ++ch) {
        const size_t base = ((size_t)b * TCH + ch) * KPAD + c * 8;
        #pragma unroll
        for (int p = 0; p < 8; ++p) {
            const float m = wsm[base + p], s = wss[base + p];
            const float Mn = fmaxf(M, m);
            S = S * expf(M - Mn) + s * expf(m - Mn);
            M = Mn;
        }
    }
    out[b * 100 + c] = M + logf(S);
}

extern "C" void kernel_launch(void* const* d_in, const int* in_sizes, int n_in,
                              void* d_out, int out_size, void* d_ws, size_t ws_size,
                              hipStream_t stream) {
    (void)in_sizes; (void)n_in; (void)out_size; (void)ws_size;
    const float* feats    = (const float*)d_in[0];
    const float* protos   = (const float*)d_in[1];
    const float* log_temp = (const float*)d_in[2];
    float* out = (float*)d_out;

    unsigned short* pn = (unsigned short*)d_ws;                        // 1.38 MB
    float* wsm   = (float*)((char*)d_ws + (size_t)KPAD * C_ * 2);      // 3.67 MB
    float* wss   = wsm + (size_t)B_ * TCH * KPAD;                      // 3.67 MB
    float* scale = wss + (size_t)B_ * TCH * KPAD;                      // 0.26 MB
    unsigned short* img = (unsigned short*)((char*)d_ws + (16u << 20)); // 96 MB @ +16MB

    proto_norm_kernel<<<KPAD, 64, 0, stream>>>(protos, pn);
    feats_img_kernel<<<B_ * TCH, 512, 0, stream>>>(feats, log_temp, img, scale);
    main_kernel<<<B_ * TCH, 512, 0, stream>>>(img, pn, scale, wsm, wss);
    final_kernel<<<B_, 128, 0, stream>>>(wsm, wss, out);
}